// Round 1
// baseline (24.077 us; speedup 1.0000x reference)
//
#include <hip/hip_runtime.h>

#define S_DIM 4
#define F_DIM 4
#define E_DIM 65536
#define NCP   32
#define PDEG  3

// knots = concat(zeros(3), linspace(0,1,30), ones(3)) -> knot(i) = clamp((i-3)/29, 0, 1)
__device__ __forceinline__ float knotv(int i) {
    float t = (float)(i - PDEG) * (1.0f / (float)(NCP - PDEG));
    return fminf(fmaxf(t, 0.0f), 1.0f);
}

// Cox-de Boor p=3 basis + first derivative (scaled by p), fully unrolled.
__device__ __forceinline__ void basis_p3(float u, int span, float N0[4], float N1[4]) {
    float left[4], right[4];
    float ndu[4][4];
    ndu[0][0] = 1.0f;
#pragma unroll
    for (int j = 1; j <= PDEG; ++j) {
        left[j]  = u - knotv(span - j + 1);
        right[j] = knotv(span + j) - u;
        float saved = 0.0f;
#pragma unroll
        for (int r = 0; r < j; ++r) {
            float denom = right[r + 1] + left[j - r];
            ndu[j][r] = denom;
            float tmp = ndu[r][j - 1] * __builtin_amdgcn_rcpf(denom);
            ndu[r][j] = saved + right[r + 1] * tmp;
            saved = left[j - r] * tmp;
        }
        ndu[j][j] = saved;
    }
#pragma unroll
    for (int j = 0; j <= PDEG; ++j) N0[j] = ndu[j][PDEG];
    // first derivative: N1[r] = p * ( ndu[r-1][p-1]/ndu[p][r-1] - ndu[r][p-1]/ndu[p][r] )
    float inv3[3];
#pragma unroll
    for (int r = 0; r < PDEG; ++r) inv3[r] = __builtin_amdgcn_rcpf(ndu[PDEG][r]);
    N1[0] = -(float)PDEG * (ndu[0][PDEG - 1] * inv3[0]);
    N1[1] =  (float)PDEG * (ndu[0][PDEG - 1] * inv3[0] - ndu[1][PDEG - 1] * inv3[1]);
    N1[2] =  (float)PDEG * (ndu[1][PDEG - 1] * inv3[1] - ndu[2][PDEG - 1] * inv3[2]);
    N1[3] =  (float)PDEG * (ndu[2][PDEG - 1] * inv3[2]);
}

__global__ __launch_bounds__(256) void nurbs_eval_kernel(
    const float* __restrict__ ep,   // (S,F,E,2)
    const float* __restrict__ cp,   // (S,F,NCP,NCP,3)
    float* __restrict__ out)        // points4 (S,F,E,4) then normals4 (S,F,E,4)
{
    __shared__ float g[NCP * NCP * 3];  // 12 KiB control patch for this (s,f)

    const int sf  = blockIdx.y;
    const int tid = threadIdx.x;

    // Stage control points for this (s,f): 3072 floats = 768 float4, 3 per thread.
    {
        const float4* src = (const float4*)(cp + (size_t)sf * (NCP * NCP * 3));
        float4* dst = (float4*)g;
#pragma unroll
        for (int t = 0; t < 3; ++t) dst[tid + t * 256] = src[tid + t * 256];
    }
    __syncthreads();

    const int e   = blockIdx.x * 256 + tid;
    const int idx = sf * E_DIM + e;

    const float2 uv = ((const float2*)ep)[idx];
    const float u = uv.x, v = uv.y;

    int su = (int)floorf(u * (float)(NCP - PDEG)) + PDEG;
    su = min(max(su, PDEG), NCP - 1);
    int sv = (int)floorf(v * (float)(NCP - PDEG)) + PDEG;
    sv = min(max(sv, PDEG), NCP - 1);

    float bu0[4], bu1[4], bv0[4], bv1[4];
    basis_p3(u, su, bu0, bu1);
    basis_p3(v, sv, bv0, bv1);

    float px = 0.f, py = 0.f, pz = 0.f;
    float dux = 0.f, duy = 0.f, duz = 0.f;
    float dvx = 0.f, dvy = 0.f, dvz = 0.f;

    const int base_u = su - PDEG;
    const int base_v = sv - PDEG;

#pragma unroll
    for (int i = 0; i < 4; ++i) {
        const float* row = &g[((base_u + i) * NCP + base_v) * 3];
        float t0x = 0.f, t0y = 0.f, t0z = 0.f;   // sum_j g * bv0[j]
        float t1x = 0.f, t1y = 0.f, t1z = 0.f;   // sum_j g * bv1[j]
#pragma unroll
        for (int j = 0; j < 4; ++j) {
            const float gx = row[3 * j + 0];
            const float gy = row[3 * j + 1];
            const float gz = row[3 * j + 2];
            const float b0 = bv0[j], b1 = bv1[j];
            t0x = fmaf(gx, b0, t0x); t0y = fmaf(gy, b0, t0y); t0z = fmaf(gz, b0, t0z);
            t1x = fmaf(gx, b1, t1x); t1y = fmaf(gy, b1, t1y); t1z = fmaf(gz, b1, t1z);
        }
        px  = fmaf(bu0[i], t0x, px);  py  = fmaf(bu0[i], t0y, py);  pz  = fmaf(bu0[i], t0z, pz);
        dux = fmaf(bu1[i], t0x, dux); duy = fmaf(bu1[i], t0y, duy); duz = fmaf(bu1[i], t0z, duz);
        dvx = fmaf(bu0[i], t1x, dvx); dvy = fmaf(bu0[i], t1y, dvy); dvz = fmaf(bu0[i], t1z, dvz);
    }

    // normal = normalize(du x dv)
    float nx = duy * dvz - duz * dvy;
    float ny = duz * dvx - dux * dvz;
    float nz = dux * dvy - duy * dvx;
    const float nn = sqrtf(nx * nx + ny * ny + nz * nz) + 1e-12f;
    const float inv = __builtin_amdgcn_rcpf(nn);
    nx *= inv; ny *= inv; nz *= inv;

    float4* outv = (float4*)out;
    outv[idx] = make_float4(px, py, pz, 1.0f);
    outv[(size_t)S_DIM * F_DIM * E_DIM + idx] = make_float4(nx, ny, nz, 0.0f);
}

extern "C" void kernel_launch(void* const* d_in, const int* in_sizes, int n_in,
                              void* d_out, int out_size, void* d_ws, size_t ws_size,
                              hipStream_t stream) {
    const float* ep = (const float*)d_in[0];
    const float* cp = (const float*)d_in[1];
    float* out = (float*)d_out;

    dim3 grid(E_DIM / 256, S_DIM * F_DIM);
    dim3 block(256);
    hipLaunchKernelGGL(nurbs_eval_kernel, grid, block, 0, stream, ep, cp, out);
}